// Round 1
// baseline (282.308 us; speedup 1.0000x reference)
//
#include <hip/hip_runtime.h>

constexpr int N_COLS = 16384;   // row length N
constexpr int HALF   = 8192;    // N/2 : half-size complex FFT length
constexpr int NT     = 512;     // threads per block; 16 complex elements per thread

// Element-index swizzle for the float2 LDS array (bank pair = index mod 16).
// Folds bits 4..7 and 8..12 into the low bits. Bijective, and XOR-LINEAR:
// S(a ^ b) = S(a) ^ S(b). Since all base/offset splits below are bit-disjoint,
// S(base + off) = S(base) ^ S(off) with S(off) a compile-time constant.
// Every access pattern in this kernel lands at the structural minimum
// (4 lanes/bank-pair for b64 = 512B/instr floor; 2-way for the b64 epilogue).
__host__ __device__ constexpr int Sc(int p) {
    return p ^ ((p >> 4) & 15) ^ ((p >> 8) & 31);
}
// 4-bit reversal (for the scatter: brev13(t + 512c) = brev13(t) ^ br4(c))
__host__ __device__ constexpr int br4(int c) {
    return ((c & 1) << 3) | ((c & 2) << 1) | ((c & 4) >> 1) | ((c & 8) >> 3);
}

// Radix-4 DIT butterfly on elements (e0,e1,e2,e3) at strides (0,s,2s,3s).
// w2 = (cw, sw) = e^{+j pi j/(2s)}; w1 = w2^2. Verbatim the verified butterfly
// from the previous kernel. With (cw,sw)=(1,0) it reduces to the pure butterfly.
__device__ __forceinline__ void bf4(float& r0, float& i0, float& r1, float& i1,
                                    float& r2, float& i2, float& r3, float& i3,
                                    float cw, float sw) {
    float c1 = cw * cw - sw * sw;
    float s1 = 2.0f * cw * sw;
    float tr, ti;
    tr = c1 * r1 - s1 * i1; ti = c1 * i1 + s1 * r1;
    r1 = r0 - tr; i1 = i0 - ti; r0 += tr; i0 += ti;
    tr = c1 * r3 - s1 * i3; ti = c1 * i3 + s1 * r3;
    r3 = r2 - tr; i3 = i2 - ti; r2 += tr; i2 += ti;
    tr = cw * r2 - sw * i2; ti = cw * i2 + sw * r2;
    r2 = r0 - tr; i2 = i0 - ti; r0 += tr; i0 += ti;
    tr = -sw * r3 - cw * i3; ti = cw * r3 - sw * i3;
    r3 = r1 - tr; i3 = i1 - ti; r1 += tr; i1 += ti;
}

// Fused register-resident radix-16 round = radix-4 stage at stride SS followed
// by radix-4 stage at stride 4*SS. Thread owns the 16 elements
//   base + SS*c1 + 4*SS*c2 ,  c1,c2 in [0,4)
// (read set == write set, so no barrier inside the round).
// Twiddles come from expk: expk[n] = e^{-j pi n/32768}, and the stage-s twiddle
// is e^{+j pi j/(2s)} = (e.x, -e.y) at n = j*16384/s.
//   stage SS  : j  = base mod SS          (one broadcast-ish load)
//   stage 4SS : j' = j + SS*c1            (four loads)
template<int SS>
__device__ __forceinline__ void round16(float2* zs, const float2* __restrict__ ek2,
                                        int sb, int j) {
    float vr[4][4], vi[4][4];
    #pragma unroll
    for (int c2 = 0; c2 < 4; ++c2)
        #pragma unroll
        for (int c1 = 0; c1 < 4; ++c1) {
            float2 v = zs[sb ^ Sc(SS * c1 + 4 * SS * c2)];
            vr[c2][c1] = v.x; vi[c2][c1] = v.y;
        }
    {   // stage at stride SS: butterfly across c1 (same twiddle for all c2)
        float2 e = ek2[j * (16384 / SS)];
        float cw = e.x, sw = -e.y;
        #pragma unroll
        for (int c2 = 0; c2 < 4; ++c2)
            bf4(vr[c2][0], vi[c2][0], vr[c2][1], vi[c2][1],
                vr[c2][2], vi[c2][2], vr[c2][3], vi[c2][3], cw, sw);
    }
    // stage at stride 4*SS: butterfly across c2, twiddle index j + SS*c1
    #pragma unroll
    for (int c1 = 0; c1 < 4; ++c1) {
        float2 e = ek2[j * (4096 / SS) + c1 * 4096];
        bf4(vr[0][c1], vi[0][c1], vr[1][c1], vi[1][c1],
            vr[2][c1], vi[2][c1], vr[3][c1], vi[3][c1], e.x, -e.y);
    }
    #pragma unroll
    for (int c2 = 0; c2 < 4; ++c2)
        #pragma unroll
        for (int c1 = 0; c1 < 4; ++c1)
            zs[sb ^ Sc(SS * c1 + 4 * SS * c2)] = make_float2(vr[c2][c1], vi[c2][c1]);
}

// One block per row. Same algorithm as before:
//   V_k = (x_k - j x_{N-k}) e^{j pi k/(2N)},  Z_k = half-size packing of V
//   8192-pt complex IDFT of Z, then y from re/im of z.
// Restructured: 13 stages = 3 fused radix-16 register rounds (s=1,4 | 16,64 |
// 256,1024) + span-4096 radix-2. float2 (b64) LDS everywhere, table twiddles
// (no __sincosf anywhere), 5 barriers, float4 coalesced output stores.
__global__ __launch_bounds__(NT, 4)
void idxct_kernel(const float* __restrict__ x,
                  const float* __restrict__ expk,
                  float* __restrict__ y)
{
    __shared__ float2 zs[HALF];   // 64 KiB -> 2 blocks/CU

    const int row = blockIdx.x;
    const float* __restrict__ xr = x + (size_t)row * N_COLS;
    float* __restrict__ yr       = y + (size_t)row * N_COLS;
    const int t   = threadIdx.x;
    const float x0 = xr[0];
    const float2* __restrict__ ek2 = (const float2*)expk;

    // ---- preprocess: Z_k -> zs[Sc(brev13(k))], k = t + 512c ----
    // brev13(t) has low 4 bits clear (t < 512), so the c-part XORs in as br4(c).
    const int spt = Sc((int)(__brev((unsigned)t) >> 19));
    #pragma unroll
    for (int c = 0; c < 16; ++c) {
        const int k = t + NT * c;
        float2 e0 = ek2[k];
        float c0 = e0.x, s0 = -e0.y;          // e^{+j pi k/(2N)}
        float vkr, vki;
        if (c == 0 && t == 0) { vkr = x0; vki = 0.0f; }
        else {
            float a = xr[k], b = xr[N_COLS - k];
            vkr = a * c0 + b * s0;            // (a - j b)(c + j s)
            vki = a * s0 - b * c0;
        }
        const int K = k + HALF;               // V_{k+H}
        float2 e1 = ek2[K];
        float c4 = e1.x, s4 = -e1.y;
        float a1 = xr[K], b1 = xr[N_COLS - K];
        float wkr = a1 * c4 + b1 * s4;
        float wki = a1 * s4 - b1 * c4;
        float dr = vkr - wkr, di = vki - wki;
        // e^{j 2 pi k/N} = (c0 + j s0)^4 (two complex squarings)
        float cA = c0 * c0 - s0 * s0, sA = 2.0f * c0 * s0;
        float ec = cA * cA - sA * sA, es = 2.0f * cA * sA;
        float zr = (vkr + wkr) - (ec * di + es * dr);
        float zi = (vki + wki) + (ec * dr - es * di);
        zs[spt ^ br4(c)] = make_float2(zr, zi);
    }

    // ---- three fused radix-16 register rounds ----
    __syncthreads();
    round16<1>(zs, ek2, Sc(t << 4), 0);                                // s = 1, 4
    __syncthreads();
    round16<16>(zs, ek2, Sc(((t >> 4) << 8) | (t & 15)), t & 15);      // s = 16, 64
    __syncthreads();
    round16<256>(zs, ek2, Sc(((t >> 8) << 12) | (t & 255)), t & 255);  // s = 256, 1024
    __syncthreads();

    // ---- final radix-2 stage, span 4096: w = e^{+j pi q/4096} ----
    // n = 8q overruns the 16384-entry table at q >= 2048; there
    // w = j * e^{+j pi (q-2048)/4096}  ->  (cw, sw) = (e.y, e.x).
    {
        const int st = Sc(t);
        #pragma unroll
        for (int c = 0; c < 8; ++c) {
            const int q   = t + NT * c;            // [0, 4096)
            const int sq  = st ^ Sc(NT * c);       // Sc(q)
            const int sq2 = sq ^ Sc(4096);         // Sc(q + 4096) = Sc(q) ^ 4096 ^ 16
            float2 a = zs[sq], b = zs[sq2];
            float cw, sw;
            if (c < 4) { float2 e = ek2[q << 3];          cw = e.x; sw = -e.y; }
            else       { float2 e = ek2[(q - 2048) << 3]; cw = e.y; sw =  e.x; }
            float tr = cw * b.x - sw * b.y;
            float ti = cw * b.y + sw * b.x;
            zs[sq]  = make_float2(a.x + tr, a.y + ti);
            zs[sq2] = make_float2(a.x - tr, a.y - ti);
        }
    }
    __syncthreads();

    // ---- epilogue: for m in [0,4096):
    //   y[4m]   = re z[m]      y[4m+2] = im z[m]
    //   y[4m+1] = im z[8191-m] y[4m+3] = re z[8191-m]
    // two b64 LDS reads -> one float4 coalesced store (16 B/lane).
    {
        const int st  = Sc(t);
        const int stc = Sc(t ^ 511);               // Sc(511 - t)
        #pragma unroll
        for (int i = 0; i < 8; ++i) {
            const int m = t + NT * i;              // [0, 4096)
            float2 a = zs[st  ^ Sc(NT * i)];       // Sc(m)
            float2 b = zs[stc ^ Sc((15 - i) << 9)];// Sc(8191 - m)
            float4 o;
            o.x = 0.5f * (a.x + x0);
            o.y = 0.5f * (b.y + x0);
            o.z = 0.5f * (a.y + x0);
            o.w = 0.5f * (b.x + x0);
            *reinterpret_cast<float4*>(yr + 4 * m) = o;
        }
    }
}

extern "C" void kernel_launch(void* const* d_in, const int* in_sizes, int n_in,
                              void* d_out, int out_size, void* d_ws, size_t ws_size,
                              hipStream_t stream)
{
    const float* x    = (const float*)d_in[0];
    const float* expk = (const float*)d_in[1];
    float* y          = (float*)d_out;
    const int M = in_sizes[0] / N_COLS;        // 2048 rows
    idxct_kernel<<<dim3(M), dim3(NT), 0, stream>>>(x, expk, y);
}